// Round 14
// baseline (228.793 us; speedup 1.0000x reference)
//
#include <hip/hip_runtime.h>
#include <hip/hip_bf16.h>

// Hopfield sparsemax attention, MI355X gfx950.
// B=1, L=S=2048, D_MODEL=1024, H=16, DK=64. Inputs fp32 (runtime-detected), output per flag.
//
// Round-23 (attn v11: software-pipelined main loop):
//   - Fold/append runs ONE STEP BEHIND loads+MFMA: per unrolled iteration,
//     {issue step s+1's 8 K-loads -> FOLD/APPEND step s (~250 cyc VALU hides the
//     L2 load latency) -> MFMA step s+1 into the alternate acc buffer}.
//     Full unroll => all buffer indices compile-time (no scratch, rule #20).
//     Per-lane append order, thresholds, and fp math order unchanged vs v8 ->
//     same determinism class (v8 tripwire-passed 3x). VGPR ~32 -> ~80;
//     __launch_bounds__(256,6).
//   - transpose4 keeps R21 conflict-free write swizzle; gemm64 v3 (8-wave) and the
//     rest unchanged from R22 (227.7 us, best).

typedef __attribute__((ext_vector_type(8))) short short8;
typedef __attribute__((ext_vector_type(4))) float floatx4;

#define SRC_BF16 0
#define SRC_F32  1
#define SRC_RT   2
#define NSEG 12           // private slots per writer lane (16 writers/row)
#define OVF 64            // shared overflow slots per row
#define OVBASE 192        // 16 * NSEG
#define CAPP 257          // padded row stride (256 slots + 1 pad)

typedef __attribute__((address_space(1))) const void GAS;
typedef __attribute__((address_space(3))) void LAS;
#define GLOAD16(g, l) __builtin_amdgcn_global_load_lds((GAS*)(g), (LAS*)(l), 16, 0, 0)

__device__ __forceinline__ short f2bf(float f) {
    __hip_bfloat16 h = __float2bfloat16(f);
    return *reinterpret_cast<const short*>(&h);
}
__device__ __forceinline__ unsigned short f2bfu(float f) {
    __hip_bfloat16 h = __float2bfloat16(f);
    return *reinterpret_cast<const unsigned short*>(&h);
}
__device__ __forceinline__ float bf2f(unsigned short u) {
    return __uint_as_float(((unsigned)u) << 16);
}
// monotone float->uint map (order-preserving for all finite floats)
__device__ __forceinline__ unsigned fmap(float f) {
    unsigned u = __float_as_uint(f);
    return (u & 0x80000000u) ? ~u : (u | 0x80000000u);
}
__device__ __forceinline__ float funmap(unsigned u) {
    return (u & 0x80000000u) ? __uint_as_float(u ^ 0x80000000u) : __uint_as_float(~u);
}

// Detect input dtype: decode first n shorts as bf16; fp32-read-as-bf16 almost surely
// yields |x|>1e10 / inf / NaN. One 64-thread block.
__global__ void detect_k(const short* __restrict__ q, int n, int* __restrict__ flag)
{
    const int tid = threadIdx.x;
    int bad = 0;
    for (int i = tid; i < n; i += 64) {
        float f = bf2f((unsigned short)q[i]);
        if (!(fabsf(f) < 1e10f)) bad = 1;
    }
    unsigned long long m = __ballot(bad != 0);
    if (tid == 0) *flag = (m != 0ULL) ? 1 : 0;
}

// Flat convert (fp32|bf16 per flag) -> bf16. z selects one of two sources.
__global__ __launch_bounds__(256)
void convert2_k(const void* __restrict__ s0, const void* __restrict__ s1,
                short* __restrict__ d0, short* __restrict__ d1,
                const int* __restrict__ dflag)
{
    const void* s = blockIdx.z ? s1 : s0;
    short* d = blockIdx.z ? d1 : d0;
    const size_t i = ((size_t)blockIdx.x * 256 + threadIdx.x) * 8;
    short8 o;
    if (*dflag) {
        const float4 f0 = ((const float4*)((const float*)s + i))[0];
        const float4 f1 = ((const float4*)((const float*)s + i))[1];
        o[0] = f2bf(f0.x); o[1] = f2bf(f0.y); o[2] = f2bf(f0.z); o[3] = f2bf(f0.w);
        o[4] = f2bf(f1.x); o[5] = f2bf(f1.y); o[6] = f2bf(f1.z); o[7] = f2bf(f1.w);
    } else {
        o = *(const short8*)((const short*)s + i);
    }
    *(short8*)(d + i) = o;
}

// Batched weight transpose: 4 matrices [R,C] -> bf16 [C,R], selected by blockIdx.z.
// LDS T[c][r ^ 8*((c>>3)&7)]: write banks fully spread; XOR is a multiple of 8 shorts
// -> short8 blocks stay contiguous & 16B-aligned.
struct TP4 {
    const void* s[4];
    short* d[4];
};
__global__ __launch_bounds__(256)
void transpose4_k(TP4 p, int R, int C, const int* __restrict__ dflag)
{
    __shared__ __align__(16) short T[64][72];
    const int tid = threadIdx.x;
    const int bC = blockIdx.x, bR = blockIdx.y;
    const void* src = p.s[blockIdx.z];
    short* dst = p.d[blockIdx.z];
    const bool f32 = (*dflag != 0);

    const int colg = (tid & 7) * 8;
    const int cswz = 8 * (tid & 7);        // = 8*(((colg+j)>>3)&7) for j<8
    #pragma unroll
    for (int h = 0; h < 2; ++h) {
        const int row = (tid >> 3) + 32 * h;
        const size_t idx = (size_t)(bR * 64 + row) * (size_t)C + (size_t)(bC * 64 + colg);
        short e[8];
        if (f32) {
            const float4 f0 = ((const float4*)((const float*)src + idx))[0];
            const float4 f1 = ((const float4*)((const float*)src + idx))[1];
            e[0] = f2bf(f0.x); e[1] = f2bf(f0.y); e[2] = f2bf(f0.z); e[3] = f2bf(f0.w);
            e[4] = f2bf(f1.x); e[5] = f2bf(f1.y); e[6] = f2bf(f1.z); e[7] = f2bf(f1.w);
        } else {
            short8 s = *(const short8*)((const short*)src + idx);
            #pragma unroll
            for (int j = 0; j < 8; ++j) e[j] = s[j];
        }
        const int rp = row ^ cswz;
        #pragma unroll
        for (int j = 0; j < 8; ++j) T[colg + j][rp] = e[j];
    }
    __syncthreads();
    #pragma unroll
    for (int h = 0; h < 2; ++h) {
        const int orow = (tid >> 3) + 32 * h;
        const int ocolg = ((tid & 7) * 8) ^ (8 * ((orow >> 3) & 7));
        const size_t idx = (size_t)(bC * 64 + orow) * (size_t)R
                         + (size_t)(bR * 64 + (((tid & 7) * 8)));
        // physical block ocolg holds logical r-block (ocolg ^ swz) = (tid&7)*8
        *(short8*)(dst + idx) = *(const short8*)&T[orow][ocolg];
    }
}

// ---------------- 64x64-tile GEMM v3: 8 waves / 512 threads, BK=64, dbuf -------------
// C = (A@Bt^T + bias) * os. Waves 2M x 4N, each 32x16 out (acc[2][1]). Staging:
// 1 gload16/thread/matrix, row tid>>3, phys colgrp tid&7 <- logical (tid&7)^((tid>>3)&7).
// ds_read swizzle pc = ((kk*4+quad)^(r16&7))*8 (involution, both sides). One barrier
// per K-step; K order identical to v2 -> bit-identical outputs.
struct GJ { const short* A; const short* B; const void* bias; void* C; float os; };

template<int OSRC>
__global__ __launch_bounds__(512)
void gemm64_bt_k(GJ j0, GJ j1, const int* __restrict__ dflag)
{
    __shared__ __align__(16) short As[2][64][64];
    __shared__ __align__(16) short Bs[2][64][64];

    const GJ j = blockIdx.z ? j1 : j0;
    const int rtf = *dflag;

    const int tid  = threadIdx.x;
    const int bN   = blockIdx.x, bM = blockIdx.y;
    const int lane = tid & 63, wave = tid >> 6;
    const int wm   = (wave >> 2) * 32;       // 2 M-groups of 32
    const int wn   = (wave & 3) * 16;        // 4 N-groups of 16
    const int quad = lane >> 4, r16 = lane & 15;

    floatx4 acc[2];
    acc[0] = (floatx4){0.f, 0.f, 0.f, 0.f};
    acc[1] = (floatx4){0.f, 0.f, 0.f, 0.f};

    // staging: thread t -> row t>>3 (0..63), phys colgrp t&7 holds logical (t&7)^((t>>3)&7)
    const int srow = tid >> 3;
    const int scg  = (tid & 7) ^ ((tid >> 3) & 7);
    const short* gA = j.A + (size_t)(bM * 64 + srow) * 1024 + scg * 8;
    const short* gB = j.B + (size_t)(bN * 64 + srow) * 1024 + scg * 8;

#define STAGE(buf, k0)                                                          \
    {                                                                           \
        GLOAD16(gA + (k0), &As[buf][wave * 8][0]);                              \
        GLOAD16(gB + (k0), &Bs[buf][wave * 8][0]);                              \
    }

    STAGE(0, 0);
    __syncthreads();

    const int sr = r16 & 7;
    int buf = 0;
    for (int t = 0; t < 16; ++t) {
        if (t < 15) STAGE(buf ^ 1, (t + 1) * 64);
        #pragma unroll
        for (int kk = 0; kk < 2; ++kk) {
            const int pc = ((kk * 4 + quad) ^ sr) * 8;
            const short8 a0 = *(const short8*)&As[buf][wm + r16][pc];
            const short8 a1 = *(const short8*)&As[buf][wm + 16 + r16][pc];
            const short8 b0 = *(const short8*)&Bs[buf][wn + r16][pc];
            acc[0] = __builtin_amdgcn_mfma_f32_16x16x32_bf16(a0, b0, acc[0], 0, 0, 0);
            acc[1] = __builtin_amdgcn_mfma_f32_16x16x32_bf16(a1, b0, acc[1], 0, 0, 0);
        }
        __syncthreads();   // drains staged loads + guards buf reuse
        buf ^= 1;
    }
#undef STAGE

    const bool of32 = (OSRC == SRC_F32) || (OSRC == SRC_RT && rtf);
    const int gc = bN * 64 + wn + r16;
    const float bb = rtf ? ((const float*)j.bias)[gc]
                         : bf2f(((const unsigned short*)j.bias)[gc]);
    #pragma unroll
    for (int i = 0; i < 2; ++i) {
        #pragma unroll
        for (int rg = 0; rg < 4; ++rg) {
            const int gr = bM * 64 + wm + i * 16 + quad * 4 + rg;
            const float v = (acc[i][rg] + bb) * j.os;
            if (of32)
                ((float*)j.C)[(size_t)gr * 1024 + gc] = v;
            else
                ((__hip_bfloat16*)j.C)[(size_t)gr * 1024 + gc] = __float2bfloat16(v);
        }
    }
}

// ---------------- fused attention v11: software-pipelined v8 -------------------------
// Block = 16 Q-rows x 1 head, 256 threads (4 waves). Wave w owns kcols [w*512,+512),
// 8 steps x 64 kcols, S^T via mfma(A=K, B=Q): lane holds S[kc][qrow=r16]. Pipeline:
// prologue computes step 0; iteration s: {issue step s+1 K-loads -> fold/append step
// s (VALU covers load latency) -> MFMA step s+1 into alternate acc}. Fold/append is
// v8 verbatim (top-2, cross-quad butterfly, quad0 atomicMax, thr = max(g1-1,
// (g1+m2-1)/2)). Tail: row-parallel Michelot + quad-ballot compact + uint2 PV.
__global__ __launch_bounds__(256, 6)
void attn_fused_k(const short* __restrict__ Qb, const short* __restrict__ Kb,
                  const short* __restrict__ Vb, short* __restrict__ Ob)
{
    __shared__ unsigned cpk[16][CAPP];
    __shared__ unsigned rmax[16];
    __shared__ int cnt[16];

    const int tid  = threadIdx.x;
    const int lane = tid & 63, wave = tid >> 6;
    const int quad = lane >> 4, r16 = lane & 15;

    // head->XCD pinning: blocks with bid%8==x carry heads x and x+8.
    const int bid  = blockIdx.x;
    const int slot = bid >> 3;
    const int h    = (slot & 1) * 8 + (bid & 7);
    const int row0 = (slot >> 1) * 16;

    if (tid < 16) { rmax[tid] = fmap(-3.0e38f); cnt[tid] = 0; }
    __syncthreads();

    // Q fragment (B-operand): col = qrow = row0 + r16, k-offset quad*8 (+32)
    const short* qp = Qb + (size_t)(row0 + r16) * 1024 + h * 64 + quad * 8;
    const short8 qb0 = *(const short8*)qp;
    const short8 qb1 = *(const short8*)(qp + 32);

    const int wid   = wave * 4 + quad;         // writer id 0..15 (per row)
    const int kbase = wave * 512;
    const short* kpA = Kb + (size_t)(kbase + r16) * 1024 + h * 64 + quad * 8;

    float rm1 = -3.0e38f, rm2 = -3.0e38f;
    int mycnt = 0;

    // v8-verbatim fold + share + append on acc array A for step S
#define FOLD_APPEND(S, A)                                                        \
    {                                                                            \
        float m1 = A[0][0], m2 = -3.0e38f;                                       \
        _Pragma("unroll")                                                        \
        for (int t = 0; t < 4; ++t) {                                            \
            _Pragma("unroll")                                                    \
            for (int rg = 0; rg < 4; ++rg) {                                     \
                if (t == 0 && rg == 0) continue;                                 \
                const float v = A[t][rg];                                        \
                m2 = fmaxf(m2, fminf(m1, v));                                    \
                m1 = fmaxf(m1, v);                                               \
            }                                                                    \
        }                                                                        \
        _Pragma("unroll")                                                        \
        for (int off = 16; off < 64; off <<= 1) {                                \
            const float o1 = __shfl_xor(m1, off, 64);                            \
            const float o2 = __shfl_xor(m2, off, 64);                            \
            const float n2 = fmaxf(fminf(m1, o1), (m1 >= o1) ? m2 : o2);         \
            m1 = fmaxf(m1, o1);                                                  \
            m2 = n2;                                                             \
        }                                                                        \
        rm2 = fmaxf(fminf(rm1, m1), (rm1 >= m1) ? rm2 : m2);                     \
        rm1 = fmaxf(rm1, m1);                                                    \
        if (quad == 0) atomicMax(&rmax[r16], fmap(m1));                          \
        const float g1 = fmaxf(funmap(rmax[r16]), rm1);                          \
        const float thr = fmaxf(g1 - 1.0f, 0.5f * (g1 + rm2) - 0.5f);            \
        _Pragma("unroll")                                                        \
        for (int t = 0; t < 4; ++t) {                                            \
            _Pragma("unroll")                                                    \
            for (int rg = 0; rg < 4; ++rg) {                                     \
                const float val = A[t][rg];                                      \
                if (val >= thr) {                                                \
                    const unsigned pk = ((unsigned)f2bfu(val) << 16)             \
                        | (unsigned)(kbase + (S) * 64 + t * 16 + quad * 4 + rg); \
                    const int c = mycnt;                                         \
                    if (c < NSEG) {                                              \
                        cpk[r16][wid * NSEG + c] = pk;                           \
                    } else {                                                     \
                        const int p = atomicAdd(&cnt[r16], 1);                   \
                        if (p < OVF) cpk[r16][OVBASE + p] = pk;                  \
                    }                                                            \
                    mycnt = c + 1;                                               \
                }                                                                \
            }                                                                    \
        }                                                                        \
    }

    floatx4 accA[4], accB[4];
    // prologue: step 0 loads + MFMA -> accA
    #pragma unroll
    for (int t = 0; t < 4; ++t) {
        const short* kp = kpA + (size_t)(t * 16) * 1024;
        const short8 a0 = *(const short8*)kp;
        const short8 a1 = *(const short8*)(kp + 32);
        floatx4 a = (floatx4){0.f, 0.f, 0.f, 0.f};
        a = __builtin_amdgcn_mfma_f32_16x16x32_bf16(a0, qb0, a, 0, 0, 0);
        a = __builtin_amdgcn_mfma_f32_16x16x32_bf16(a1, qb1, a, 0, 0, 0);
        accA[t] = a;   // scale 1/8 pre-folded into Qb
    }

    #pragma unroll
    for (int s = 0; s < 8; ++s) {
        short8 kr[8];
        if (s < 7) {
            #pragma unroll
            for (int t = 0; t < 4; ++t) {
                const short* kp = kpA + (size_t)((s + 1) * 64 + t * 16) * 1024;
                kr[t * 2]     = *(const short8*)kp;
                kr[t * 2 + 1] = *(const short8*)(kp + 32);
            }
        }
        // fold/append current step (VALU work hides the just-issued loads)
        if (s & 1) { FOLD_APPEND(s, accB) } else { FOLD_APPEND(s, accA) }
        // MFMA next step into the alternate buffer
        if (s < 7) {
            #pragma unroll
            for (int t = 0; t < 4; ++t) {
                floatx4 a = (floatx4){0.f, 0.f, 0.f, 0.f};
                a = __builtin_amdgcn_mfma_f32_16x16x32_bf16(kr[t * 2], qb0, a, 0, 0, 0);
                a = __builtin_amdgcn_mfma_f32_16x16x32_bf16(kr[t * 2 + 1], qb1, a, 0, 0, 0);
                if (s & 1) accA[t] = a; else accB[t] = a;
            }
        }
    }
#undef FOLD_APPEND

    // sentinel-fill unused private slots (bf16 -inf packed)
    for (int k = mycnt; k < NSEG; ++k)
        cpk[r16][wid * NSEG + k] = 0xFF800000u;
    __syncthreads();   // all appends + final rmax visible

    // ---- row-parallel tail: quad q of wave w owns row 4w+q ----
    const int r = wave * 4 + quad;
    const int novf = min(cnt[r], OVF);

    // 16 candidates per lane; k>=12 are overflow slots, guarded by novf
    unsigned ca[16];
    #pragma unroll
    for (int k = 0; k < 12; ++k) ca[k] = cpk[r][k * 16 + r16];
    #pragma unroll
    for (int k = 12; k < 16; ++k) {
        const int oi = k * 16 + r16 - OVBASE;
        ca[k] = (oi < novf) ? cpk[r][k * 16 + r16] : 0xFF800000u;
    }

    // Michelot from exact tau0 = g1-1 (monotone increasing; sentinels never activate)
    float tau = funmap(rmax[r]) - 1.0f;
    float prevc = -1.0f;
    for (int it = 0; it < 18; ++it) {
        float s = 0.f, c = 0.f;
        #pragma unroll
        for (int k = 0; k < 16; ++k) {
            const float v = __uint_as_float(ca[k] & 0xFFFF0000u);
            if (v > tau) { s += v; c += 1.f; }
        }
        #pragma unroll
        for (int off = 1; off < 16; off <<= 1) {
            s += __shfl_xor(s, off, 64);
            c += __shfl_xor(c, off, 64);
        }
        if (c == prevc || c == 0.f) break;
        prevc = c;
        tau = (s - 1.0f) / c;
    }

    // quad-ballot compact of support (p>0) to list front, p packed bf16
    const unsigned qpre = (1u << r16) - 1u;
    int base = 0;
    #pragma unroll
    for (int k = 0; k < 16; ++k) {
        const float v = __uint_as_float(ca[k] & 0xFFFF0000u);
        const float p = v - tau;
        const bool keep = (p > 0.f);
        const unsigned long long mm = __ballot(keep);
        const unsigned qm = (unsigned)((mm >> (quad * 16)) & 0xFFFFull);
        if (keep)
            cpk[r][base + __popc(qm & qpre)] =
                ((unsigned)f2bfu(p) << 16) | (ca[k] & 0xFFFFu);
        base += __popc(qm);
    }
    const int msup = base;

    // PV gather: lane covers out cols r16*4..+3 (uint2); rows parallel across quads
    const unsigned short* vb = (const unsigned short*)Vb + (size_t)h * 64 + r16 * 4;
    float o0 = 0.f, o1 = 0.f, o2 = 0.f, o3 = 0.f;
    int jj = 0;
    for (; jj + 2 <= msup; jj += 2) {
        const unsigned ua = cpk[r][jj], ub = cpk[r][jj + 1];
        const float pa = __uint_as_float(ua & 0xFFFF0000u);
        const float pb = __uint_as_float(ub & 0xFFFF0000u);
        const uint2 da = *(const uint2*)(vb + (size_t)(ua & 0xFFFFu) * 1024);
        const uint2 db = *(const uint2*)(vb + (size_t)(ub & 0xFFFFu) * 1024);
        o0 += pa * __uint_as_float(da.x << 16);
        o1 += pa * __uint_as_float(da.x & 0xFFFF0000u);
        o2 += pa * __uint_as_float(da.y << 16);
        o3 += pa * __uint_as_float(da.y & 0xFFFF0000u);
        o0 += pb * __uint_as_float(db.x << 16);
        o1 += pb * __uint_as_float(db.x & 0xFFFF0000u);
        o2 += pb * __uint_as_float(db.y << 16);
        o3 += pb * __uint_as_float(db.y & 0xFFFF0000u);
    }
    if (jj < msup) {
        const unsigned ua = cpk[r][jj];
        const float pa = __uint_as_float(ua & 0xFFFF0000u);
        const uint2 da = *(const uint2*)(vb + (size_t)(ua & 0xFFFFu) * 1024);
        o0 += pa * __uint_as_float(da.x << 16);
        o1 += pa * __uint_as_float(da.x & 0xFFFF0000u);
        o2 += pa * __uint_as_float(da.y << 16);
        o3 += pa * __uint_as_float(da.y & 0xFFFF0000u);
    }

    short* op = Ob + ((size_t)h * 2048 + row0 + r) * 64 + r16 * 4;
    op[0] = f2bf(o0); op[1] = f2bf(o1); op[2] = f2bf(o2); op[3] = f2bf(o3);
}

extern "C" void kernel_launch(void* const* d_in, const int* in_sizes, int n_in,
                              void* d_out, int out_size, void* d_ws, size_t ws_size,
                              hipStream_t stream)
{
    (void)in_sizes; (void)n_in; (void)out_size; (void)ws_size;

    const void* queries = d_in[0];
    const void* keys    = d_in[1];
    // d_in[2] ("values") unused by the reference.
    const void* Wq = d_in[3];
    const void* bq = d_in[4];
    const void* Wk = d_in[5];
    const void* bk = d_in[6];
    const void* Wv = d_in[7];
    const void* bv = d_in[8];
    const void* Wo = d_in[9];
    const void* bo = d_in[10];

    const int L = 2048, DM = 1024;
    const size_t LD = (size_t)L * DM;   // 2M elements

    int*   flag = (int*)d_ws;
    short* Qc  = (short*)((char*)d_ws + 256);  // bf16 queries      [2048,1024]
    short* Kc  = Qc + LD;                      // bf16 keys         [2048,1024]
    short* WqT = Kc + LD;                      // bf16 Wq^T         [1024,1024]
    short* WkT = WqT + (size_t)DM * DM;
    short* WvT = WkT + (size_t)DM * DM;
    short* WoT = WvT + (size_t)DM * DM;
    short* Qb  = WoT + (size_t)DM * DM;        // [2048,1024] (pre-scaled by 1/8)
    short* Kb  = Qb + LD;
    short* Vb  = Kb + LD;
    short* Ob  = Vb + LD;                      // [H,2048,64] contiguous (== mixed view)

    dim3 blk(256), blk2(512);

    // 0) dtype detection
    detect_k<<<dim3(1), dim3(64), 0, stream>>>((const short*)queries, 4096, flag);

    // p1) convert queries/keys -> bf16
    convert2_k<<<dim3((unsigned)(LD / 2048), 1, 2), blk, 0, stream>>>(
        queries, keys, Qc, Kc, flag);

    // p2) transpose-convert the 4 weight matrices -> bf16 [N][K]
    {
        TP4 p;
        p.s[0] = Wq; p.s[1] = Wk; p.s[2] = Wv; p.s[3] = Wo;
        p.d[0] = WqT; p.d[1] = WkT; p.d[2] = WvT; p.d[3] = WoT;
        transpose4_k<<<dim3(DM / 64, DM / 64, 4), blk, 0, stream>>>(p, DM, DM, flag);
    }

    // 1) Qb & Kb projections batched (Q job pre-scales by 1/8; exact pow2)
    {
        GJ jq{(const short*)Qc, WqT, bq, Qb, 0.125f};
        GJ jk{(const short*)Kc, WkT, bk, Kb, 1.0f};
        gemm64_bt_k<SRC_BF16><<<dim3(DM / 64, L / 64, 2), blk2, 0, stream>>>(jq, jk, flag);
    }
    // 2) Vb = Kb @ WvT + bv   (reference quirk: V from key projection)
    {
        GJ jv{(const short*)Kb, WvT, bv, Vb, 1.0f};
        gemm64_bt_k<SRC_BF16><<<dim3(DM / 64, L / 64, 1), blk2, 0, stream>>>(jv, jv, flag);
    }

    // 3) fused attention (scores never reach HBM; barrier-free main loop)
    attn_fused_k<<<dim3((L / 16) * 16), blk, 0, stream>>>(Qb, Kb, Vb, Ob);

    // 4) out = Ob(viewed [2048,1024]) @ WoT + bo -> d_out (dtype per flag)
    {
        GJ jo{(const short*)Ob, WoT, bo, d_out, 1.0f};
        gemm64_bt_k<SRC_RT><<<dim3(DM / 64, L / 64, 1), blk2, 0, stream>>>(jo, jo, flag);
    }
}

// Round 15
// 227.139 us; speedup vs baseline: 1.0073x; 1.0073x over previous
//
#include <hip/hip_runtime.h>
#include <hip/hip_bf16.h>

// Hopfield sparsemax attention, MI355X gfx950.
// B=1, L=S=2048, D_MODEL=1024, H=16, DK=64. Inputs fp32 (runtime-detected), output per flag.
//
// Round-24 (launch-count collapse, 7 -> 5):
//   - detect kernel removed: every kernel self-detects (each wave reads the same
//     first 4096 shorts of queries, __ballot -> wave-uniform verdict; identical data
//     => identical verdict; deterministic). Removes a launch + a dependency edge.
//   - convert2 + transpose4 fused into prep_k (3072 blocks: 0-2047 convert Q/K,
//     2048-3071 transpose 4 weight mats). Same per-block code -> bit-identical.
//   - gemm64 v3: flag via wave-0 self-detect + LDS broadcast reusing the existing
//     first barrier. Otherwise verbatim R22.
//   - attn v8 verbatim (R22; R23's source-level pipelining was compiler-defeated:
//     75->77 us, loads re-sunk to use sites).
//   Launches: prep -> projQK(z2) -> projV -> attn -> projO.

typedef __attribute__((ext_vector_type(8))) short short8;
typedef __attribute__((ext_vector_type(4))) float floatx4;

#define SRC_BF16 0
#define SRC_F32  1
#define SRC_RT   2
#define NSEG 12           // private slots per writer lane (16 writers/row)
#define OVF 64            // shared overflow slots per row
#define OVBASE 192        // 16 * NSEG
#define CAPP 257          // padded row stride (256 slots + 1 pad)

typedef __attribute__((address_space(1))) const void GAS;
typedef __attribute__((address_space(3))) void LAS;
#define GLOAD16(g, l) __builtin_amdgcn_global_load_lds((GAS*)(g), (LAS*)(l), 16, 0, 0)

__device__ __forceinline__ short f2bf(float f) {
    __hip_bfloat16 h = __float2bfloat16(f);
    return *reinterpret_cast<const short*>(&h);
}
__device__ __forceinline__ unsigned short f2bfu(float f) {
    __hip_bfloat16 h = __float2bfloat16(f);
    return *reinterpret_cast<const unsigned short*>(&h);
}
__device__ __forceinline__ float bf2f(unsigned short u) {
    return __uint_as_float(((unsigned)u) << 16);
}
// monotone float->uint map (order-preserving for all finite floats)
__device__ __forceinline__ unsigned fmap(float f) {
    unsigned u = __float_as_uint(f);
    return (u & 0x80000000u) ? ~u : (u | 0x80000000u);
}
__device__ __forceinline__ float funmap(unsigned u) {
    return (u & 0x80000000u) ? __uint_as_float(u ^ 0x80000000u) : __uint_as_float(~u);
}

// Wave-uniform dtype detection: decode the first 4096 shorts of q as bf16;
// fp32-read-as-bf16 almost surely yields |x|>1e10 / inf / NaN somewhere in 4096.
// Every wave computes the same verdict from the same data -> deterministic.
__device__ __forceinline__ int self_detect(const short* __restrict__ q)
{
    const int lane = threadIdx.x & 63;
    int bad = 0;
    #pragma unroll
    for (int i = 0; i < 8; ++i) {
        const short8 v = *(const short8*)(q + ((size_t)(i * 64 + lane)) * 8);
        #pragma unroll
        for (int j = 0; j < 8; ++j) {
            const float f = bf2f((unsigned short)v[j]);
            if (!(fabsf(f) < 1e10f)) bad = 1;
        }
    }
    return (__ballot(bad != 0) != 0ULL) ? 1 : 0;
}

// ---------------- prep: fused convert (Q,K -> bf16) + transpose4 (weights) ----------
// Blocks 0..2047: convert (b>>10 selects queries/keys, b&1023 is the slice).
// Blocks 2048..3071: transpose ( (b-2048)>>8 selects matrix, 16x16 tile grid ).
// Transpose LDS uses R21's conflict-free XOR write swizzle. Bit-identical outputs.
struct PREP {
    const void* q; const void* k;
    short* qd; short* kd;
    const void* ws[4];
    short* wd[4];
};
__global__ __launch_bounds__(256)
void prep_k(PREP p)
{
    __shared__ __align__(16) short T[64][72];
    const int tid = threadIdx.x;
    const int b   = blockIdx.x;
    const int f32 = self_detect((const short*)p.q);

    if (b < 2048) {
        // ---- convert slice ----
        const void* s = (b >> 10) ? p.k : p.q;
        short* d = (b >> 10) ? p.kd : p.qd;
        const size_t i = ((size_t)(b & 1023) * 256 + tid) * 8;
        short8 o;
        if (f32) {
            const float4 f0 = ((const float4*)((const float*)s + i))[0];
            const float4 f1 = ((const float4*)((const float*)s + i))[1];
            o[0] = f2bf(f0.x); o[1] = f2bf(f0.y); o[2] = f2bf(f0.z); o[3] = f2bf(f0.w);
            o[4] = f2bf(f1.x); o[5] = f2bf(f1.y); o[6] = f2bf(f1.z); o[7] = f2bf(f1.w);
        } else {
            o = *(const short8*)((const short*)s + i);
        }
        *(short8*)(d + i) = o;
        return;
    }

    // ---- transpose tile ----
    const int b2 = b - 2048;
    const int m  = b2 >> 8;
    const int rem = b2 & 255;
    const int bC = rem & 15, bR = rem >> 4;
    const void* src = p.ws[m];
    short* dst = p.wd[m];
    const int C = 1024, R = 1024;

    const int colg = (tid & 7) * 8;
    const int cswz = 8 * (tid & 7);        // = 8*(((colg+j)>>3)&7) for j<8
    #pragma unroll
    for (int h = 0; h < 2; ++h) {
        const int row = (tid >> 3) + 32 * h;
        const size_t idx = (size_t)(bR * 64 + row) * (size_t)C + (size_t)(bC * 64 + colg);
        short e[8];
        if (f32) {
            const float4 f0 = ((const float4*)((const float*)src + idx))[0];
            const float4 f1 = ((const float4*)((const float*)src + idx))[1];
            e[0] = f2bf(f0.x); e[1] = f2bf(f0.y); e[2] = f2bf(f0.z); e[3] = f2bf(f0.w);
            e[4] = f2bf(f1.x); e[5] = f2bf(f1.y); e[6] = f2bf(f1.z); e[7] = f2bf(f1.w);
        } else {
            short8 s = *(const short8*)((const short*)src + idx);
            #pragma unroll
            for (int j = 0; j < 8; ++j) e[j] = s[j];
        }
        const int rp = row ^ cswz;
        #pragma unroll
        for (int j = 0; j < 8; ++j) T[colg + j][rp] = e[j];
    }
    __syncthreads();
    #pragma unroll
    for (int h = 0; h < 2; ++h) {
        const int orow = (tid >> 3) + 32 * h;
        const int ocolg = ((tid & 7) * 8) ^ (8 * ((orow >> 3) & 7));
        const size_t idx = (size_t)(bC * 64 + orow) * (size_t)R
                         + (size_t)(bR * 64 + (((tid & 7) * 8)));
        // physical block ocolg holds logical r-block (ocolg ^ swz) = (tid&7)*8
        *(short8*)(dst + idx) = *(const short8*)&T[orow][ocolg];
    }
}

// ---------------- 64x64-tile GEMM v3: 8 waves / 512 threads, BK=64, dbuf -------------
// C = (A@Bt^T + bias) * os. Waves 2M x 4N, each 32x16 out (acc[2][1]). Staging:
// 1 gload16/thread/matrix, row tid>>3, phys colgrp tid&7 <- logical (tid&7)^((tid>>3)&7).
// ds_read swizzle pc = ((kk*4+quad)^(r16&7))*8 (involution, both sides). One barrier
// per K-step; K order identical to v2 -> bit-identical outputs. Flag: wave-0
// self-detect + LDS broadcast across the existing first barrier.
struct GJ { const short* A; const short* B; const void* bias; void* C; float os; };

template<int OSRC>
__global__ __launch_bounds__(512)
void gemm64_bt_k(GJ j0, GJ j1, const short* __restrict__ qdet)
{
    __shared__ __align__(16) short As[2][64][64];
    __shared__ __align__(16) short Bs[2][64][64];
    __shared__ int sflag;

    const GJ j = blockIdx.z ? j1 : j0;

    const int tid  = threadIdx.x;
    const int bN   = blockIdx.x, bM = blockIdx.y;
    const int lane = tid & 63, wave = tid >> 6;
    const int wm   = (wave >> 2) * 32;       // 2 M-groups of 32
    const int wn   = (wave & 3) * 16;        // 4 N-groups of 16
    const int quad = lane >> 4, r16 = lane & 15;

    floatx4 acc[2];
    acc[0] = (floatx4){0.f, 0.f, 0.f, 0.f};
    acc[1] = (floatx4){0.f, 0.f, 0.f, 0.f};

    // staging: thread t -> row t>>3 (0..63), phys colgrp t&7 holds logical (t&7)^((t>>3)&7)
    const int srow = tid >> 3;
    const int scg  = (tid & 7) ^ ((tid >> 3) & 7);
    const short* gA = j.A + (size_t)(bM * 64 + srow) * 1024 + scg * 8;
    const short* gB = j.B + (size_t)(bN * 64 + srow) * 1024 + scg * 8;

#define STAGE(buf, k0)                                                          \
    {                                                                           \
        GLOAD16(gA + (k0), &As[buf][wave * 8][0]);                              \
        GLOAD16(gB + (k0), &Bs[buf][wave * 8][0]);                              \
    }

    if (wave == 0) {
        const int det = self_detect(qdet);
        if (lane == 0) sflag = det;
    }
    STAGE(0, 0);
    __syncthreads();                          // flag broadcast rides this barrier

    const int sr = r16 & 7;
    int buf = 0;
    for (int t = 0; t < 16; ++t) {
        if (t < 15) STAGE(buf ^ 1, (t + 1) * 64);
        #pragma unroll
        for (int kk = 0; kk < 2; ++kk) {
            const int pc = ((kk * 4 + quad) ^ sr) * 8;
            const short8 a0 = *(const short8*)&As[buf][wm + r16][pc];
            const short8 a1 = *(const short8*)&As[buf][wm + 16 + r16][pc];
            const short8 b0 = *(const short8*)&Bs[buf][wn + r16][pc];
            acc[0] = __builtin_amdgcn_mfma_f32_16x16x32_bf16(a0, b0, acc[0], 0, 0, 0);
            acc[1] = __builtin_amdgcn_mfma_f32_16x16x32_bf16(a1, b0, acc[1], 0, 0, 0);
        }
        __syncthreads();   // drains staged loads + guards buf reuse
        buf ^= 1;
    }
#undef STAGE

    const int rtf = sflag;
    const bool of32 = (OSRC == SRC_F32) || (OSRC == SRC_RT && rtf);
    const int gc = bN * 64 + wn + r16;
    const float bb = rtf ? ((const float*)j.bias)[gc]
                         : bf2f(((const unsigned short*)j.bias)[gc]);
    #pragma unroll
    for (int i = 0; i < 2; ++i) {
        #pragma unroll
        for (int rg = 0; rg < 4; ++rg) {
            const int gr = bM * 64 + wm + i * 16 + quad * 4 + rg;
            const float v = (acc[i][rg] + bb) * j.os;
            if (of32)
                ((float*)j.C)[(size_t)gr * 1024 + gc] = v;
            else
                ((__hip_bfloat16*)j.C)[(size_t)gr * 1024 + gc] = __float2bfloat16(v);
        }
    }
}

// ---------------- fused attention v8: swapped-operand main loop (R22, verbatim) ------
__global__ __launch_bounds__(256, 8)
void attn_fused_k(const short* __restrict__ Qb, const short* __restrict__ Kb,
                  const short* __restrict__ Vb, short* __restrict__ Ob)
{
    __shared__ unsigned cpk[16][CAPP];
    __shared__ unsigned rmax[16];
    __shared__ int cnt[16];

    const int tid  = threadIdx.x;
    const int lane = tid & 63, wave = tid >> 6;
    const int quad = lane >> 4, r16 = lane & 15;

    // head->XCD pinning: blocks with bid%8==x carry heads x and x+8.
    const int bid  = blockIdx.x;
    const int slot = bid >> 3;
    const int h    = (slot & 1) * 8 + (bid & 7);
    const int row0 = (slot >> 1) * 16;

    if (tid < 16) { rmax[tid] = fmap(-3.0e38f); cnt[tid] = 0; }
    __syncthreads();

    // Q fragment (B-operand): col = qrow = row0 + r16, k-offset quad*8 (+32)
    const short* qp = Qb + (size_t)(row0 + r16) * 1024 + h * 64 + quad * 8;
    const short8 qb0 = *(const short8*)qp;
    const short8 qb1 = *(const short8*)(qp + 32);

    const int wid   = wave * 4 + quad;         // writer id 0..15 (per row)
    const int kbase = wave * 512;
    const short* kpA = Kb + (size_t)(kbase + r16) * 1024 + h * 64 + quad * 8;

    float rm1 = -3.0e38f, rm2 = -3.0e38f;
    int mycnt = 0;

    for (int s = 0; s < 8; ++s) {   // 8 steps x 64 kcols
        floatx4 acc[4];
        #pragma unroll
        for (int t = 0; t < 4; ++t) {
            const short* kp = kpA + (size_t)(s * 64 + t * 16) * 1024;
            const short8 a0 = *(const short8*)kp;
            const short8 a1 = *(const short8*)(kp + 32);
            floatx4 a = (floatx4){0.f, 0.f, 0.f, 0.f};
            a = __builtin_amdgcn_mfma_f32_16x16x32_bf16(a0, qb0, a, 0, 0, 0);
            a = __builtin_amdgcn_mfma_f32_16x16x32_bf16(a1, qb1, a, 0, 0, 0);
            acc[t] = a;   // scale 1/8 pre-folded into Qb
        }

        // lane-local top-2 over 16 values (all belong to row r16)
        float m1 = acc[0][0], m2 = -3.0e38f;
        #pragma unroll
        for (int t = 0; t < 4; ++t) {
            #pragma unroll
            for (int rg = 0; rg < 4; ++rg) {
                if (t == 0 && rg == 0) continue;
                const float v = acc[t][rg];
                m2 = fmaxf(m2, fminf(m1, v));
                m1 = fmaxf(m1, v);
            }
        }
        // cross-quad top-2 butterfly (same r16 = same row), offsets 16, 32
        #pragma unroll
        for (int off = 16; off < 64; off <<= 1) {
            const float o1 = __shfl_xor(m1, off, 64);
            const float o2 = __shfl_xor(m2, off, 64);
            const float n2 = fmaxf(fminf(m1, o1), (m1 >= o1) ? m2 : o2);
            m1 = fmaxf(m1, o1);
            m2 = n2;
        }
        // merge into running top-2; post m1 (16-parallel, distinct banks)
        rm2 = fmaxf(fminf(rm1, m1), (rm1 >= m1) ? rm2 : m2);
        rm1 = fmaxf(rm1, m1);
        if (quad == 0) atomicMax(&rmax[r16], fmap(m1));

        // per-lane append: thr = max(g1-1, (g1+m2-1)/2) <= tau (superset of support)
        const float g1 = fmaxf(funmap(rmax[r16]), rm1);
        const float thr = fmaxf(g1 - 1.0f, 0.5f * (g1 + rm2) - 0.5f);
        #pragma unroll
        for (int t = 0; t < 4; ++t) {
            #pragma unroll
            for (int rg = 0; rg < 4; ++rg) {
                const float val = acc[t][rg];
                if (val >= thr) {
                    const unsigned pk = ((unsigned)f2bfu(val) << 16)
                        | (unsigned)(kbase + s * 64 + t * 16 + quad * 4 + rg);
                    const int c = mycnt;
                    if (c < NSEG) {
                        cpk[r16][wid * NSEG + c] = pk;
                    } else {
                        const int p = atomicAdd(&cnt[r16], 1);
                        if (p < OVF) cpk[r16][OVBASE + p] = pk;
                    }
                    mycnt = c + 1;
                }
            }
        }
    }

    // sentinel-fill unused private slots (bf16 -inf packed)
    for (int k = mycnt; k < NSEG; ++k)
        cpk[r16][wid * NSEG + k] = 0xFF800000u;
    __syncthreads();   // all appends + final rmax visible

    // ---- row-parallel tail: quad q of wave w owns row 4w+q ----
    const int r = wave * 4 + quad;
    const int novf = min(cnt[r], OVF);

    // 16 candidates per lane; k>=12 are overflow slots, guarded by novf
    unsigned ca[16];
    #pragma unroll
    for (int k = 0; k < 12; ++k) ca[k] = cpk[r][k * 16 + r16];
    #pragma unroll
    for (int k = 12; k < 16; ++k) {
        const int oi = k * 16 + r16 - OVBASE;
        ca[k] = (oi < novf) ? cpk[r][k * 16 + r16] : 0xFF800000u;
    }

    // Michelot from exact tau0 = g1-1 (monotone increasing; sentinels never activate)
    float tau = funmap(rmax[r]) - 1.0f;
    float prevc = -1.0f;
    for (int it = 0; it < 18; ++it) {
        float s = 0.f, c = 0.f;
        #pragma unroll
        for (int k = 0; k < 16; ++k) {
            const float v = __uint_as_float(ca[k] & 0xFFFF0000u);
            if (v > tau) { s += v; c += 1.f; }
        }
        #pragma unroll
        for (int off = 1; off < 16; off <<= 1) {
            s += __shfl_xor(s, off, 64);
            c += __shfl_xor(c, off, 64);
        }
        if (c == prevc || c == 0.f) break;
        prevc = c;
        tau = (s - 1.0f) / c;
    }

    // quad-ballot compact of support (p>0) to list front, p packed bf16
    const unsigned qpre = (1u << r16) - 1u;
    int base = 0;
    #pragma unroll
    for (int k = 0; k < 16; ++k) {
        const float v = __uint_as_float(ca[k] & 0xFFFF0000u);
        const float p = v - tau;
        const bool keep = (p > 0.f);
        const unsigned long long mm = __ballot(keep);
        const unsigned qm = (unsigned)((mm >> (quad * 16)) & 0xFFFFull);
        if (keep)
            cpk[r][base + __popc(qm & qpre)] =
                ((unsigned)f2bfu(p) << 16) | (ca[k] & 0xFFFFu);
        base += __popc(qm);
    }
    const int msup = base;

    // PV gather: lane covers out cols r16*4..+3 (uint2); rows parallel across quads
    const unsigned short* vb = (const unsigned short*)Vb + (size_t)h * 64 + r16 * 4;
    float o0 = 0.f, o1 = 0.f, o2 = 0.f, o3 = 0.f;
    int jj = 0;
    for (; jj + 2 <= msup; jj += 2) {
        const unsigned ua = cpk[r][jj], ub = cpk[r][jj + 1];
        const float pa = __uint_as_float(ua & 0xFFFF0000u);
        const float pb = __uint_as_float(ub & 0xFFFF0000u);
        const uint2 da = *(const uint2*)(vb + (size_t)(ua & 0xFFFFu) * 1024);
        const uint2 db = *(const uint2*)(vb + (size_t)(ub & 0xFFFFu) * 1024);
        o0 += pa * __uint_as_float(da.x << 16);
        o1 += pa * __uint_as_float(da.x & 0xFFFF0000u);
        o2 += pa * __uint_as_float(da.y << 16);
        o3 += pa * __uint_as_float(da.y & 0xFFFF0000u);
        o0 += pb * __uint_as_float(db.x << 16);
        o1 += pb * __uint_as_float(db.x & 0xFFFF0000u);
        o2 += pb * __uint_as_float(db.y << 16);
        o3 += pb * __uint_as_float(db.y & 0xFFFF0000u);
    }
    if (jj < msup) {
        const unsigned ua = cpk[r][jj];
        const float pa = __uint_as_float(ua & 0xFFFF0000u);
        const uint2 da = *(const uint2*)(vb + (size_t)(ua & 0xFFFFu) * 1024);
        o0 += pa * __uint_as_float(da.x << 16);
        o1 += pa * __uint_as_float(da.x & 0xFFFF0000u);
        o2 += pa * __uint_as_float(da.y << 16);
        o3 += pa * __uint_as_float(da.y & 0xFFFF0000u);
    }

    short* op = Ob + ((size_t)h * 2048 + row0 + r) * 64 + r16 * 4;
    op[0] = f2bf(o0); op[1] = f2bf(o1); op[2] = f2bf(o2); op[3] = f2bf(o3);
}

extern "C" void kernel_launch(void* const* d_in, const int* in_sizes, int n_in,
                              void* d_out, int out_size, void* d_ws, size_t ws_size,
                              hipStream_t stream)
{
    (void)in_sizes; (void)n_in; (void)out_size; (void)ws_size;

    const void* queries = d_in[0];
    const void* keys    = d_in[1];
    // d_in[2] ("values") unused by the reference.
    const void* Wq = d_in[3];
    const void* bq = d_in[4];
    const void* Wk = d_in[5];
    const void* bk = d_in[6];
    const void* Wv = d_in[7];
    const void* bv = d_in[8];
    const void* Wo = d_in[9];
    const void* bo = d_in[10];

    const int L = 2048, DM = 1024;
    const size_t LD = (size_t)L * DM;   // 2M elements

    short* Qc  = (short*)((char*)d_ws + 256);  // bf16 queries      [2048,1024]
    short* Kc  = Qc + LD;                      // bf16 keys         [2048,1024]
    short* WqT = Kc + LD;                      // bf16 Wq^T         [1024,1024]
    short* WkT = WqT + (size_t)DM * DM;
    short* WvT = WkT + (size_t)DM * DM;
    short* WoT = WvT + (size_t)DM * DM;
    short* Qb  = WoT + (size_t)DM * DM;        // [2048,1024] (pre-scaled by 1/8)
    short* Kb  = Qb + LD;
    short* Vb  = Kb + LD;
    short* Ob  = Vb + LD;                      // [H,2048,64] contiguous (== mixed view)

    dim3 blk(256), blk2(512);
    const short* qdet = (const short*)queries;

    // p) fused convert + weight transpose (self-detecting)
    {
        PREP pp;
        pp.q = queries; pp.k = keys; pp.qd = Qc; pp.kd = Kc;
        pp.ws[0] = Wq; pp.ws[1] = Wk; pp.ws[2] = Wv; pp.ws[3] = Wo;
        pp.wd[0] = WqT; pp.wd[1] = WkT; pp.wd[2] = WvT; pp.wd[3] = WoT;
        prep_k<<<dim3(3072), blk, 0, stream>>>(pp);
    }

    // 1) Qb & Kb projections batched (Q job pre-scales by 1/8; exact pow2)
    {
        GJ jq{(const short*)Qc, WqT, bq, Qb, 0.125f};
        GJ jk{(const short*)Kc, WkT, bk, Kb, 1.0f};
        gemm64_bt_k<SRC_BF16><<<dim3(DM / 64, L / 64, 2), blk2, 0, stream>>>(jq, jk, qdet);
    }
    // 2) Vb = Kb @ WvT + bv   (reference quirk: V from key projection)
    {
        GJ jv{(const short*)Kb, WvT, bv, Vb, 1.0f};
        gemm64_bt_k<SRC_BF16><<<dim3(DM / 64, L / 64, 1), blk2, 0, stream>>>(jv, jv, qdet);
    }

    // 3) fused attention (scores never reach HBM; barrier-free main loop)
    attn_fused_k<<<dim3((L / 16) * 16), blk, 0, stream>>>(Qb, Kb, Vb, Ob);

    // 4) out = Ob(viewed [2048,1024]) @ WoT + bo -> d_out (dtype per flag)
    {
        GJ jo{(const short*)Ob, WoT, bo, d_out, 1.0f};
        gemm64_bt_k<SRC_RT><<<dim3(DM / 64, L / 64, 1), blk2, 0, stream>>>(jo, jo, qdet);
    }
}